// Round 6
// baseline (68.072 us; speedup 1.0000x reference)
//
#include <hip/hip_runtime.h>

#define S_LEN 2048
#define HID   1280
#define NH    16
#define HD    80
#define WIN   64
#define NWIN  (S_LEN / WIN)

typedef _Float16 half4v __attribute__((ext_vector_type(4)));
typedef _Float16 half8v __attribute__((ext_vector_type(8)));
typedef float    float4v __attribute__((ext_vector_type(4)));

// async global->LDS, 16B per lane. LDS dest = wave-uniform base (HW adds lane*16);
// global src is per-lane.
__device__ __forceinline__ void gload16(const _Float16* g, _Float16* l)
{
    __builtin_amdgcn_global_load_lds((const __attribute__((address_space(1))) void*)g,
                                     (__attribute__((address_space(3))) void*)l,
                                     16, 0, 0);
}

// counted vmcnt wait (T4). Literal immediates required.
template <int N>
__device__ __forceinline__ void waitcnt_vm()
{
    if constexpr (N == 0)      asm volatile("s_waitcnt vmcnt(0)" ::: "memory");
    else if constexpr (N == 3) asm volatile("s_waitcnt vmcnt(3)" ::: "memory");
    else if constexpr (N == 6) asm volatile("s_waitcnt vmcnt(6)" ::: "memory");
    else static_assert(N < 0, "add literal");
}

__device__ __forceinline__ void cfence() { asm volatile("" ::: "memory"); }

// ---------------- merged fp32 -> fp16 conversion (3 buffers, one launch) ----------------
__global__ void cvt_all(const float* __restrict__ a, _Float16* __restrict__ oa, int na4,
                        const float* __restrict__ b, _Float16* __restrict__ ob, int nb4,
                        const float* __restrict__ c, _Float16* __restrict__ oc, int nc4)
{
    int i = blockIdx.x * blockDim.x + threadIdx.x;
    const float* in; _Float16* out; int idx;
    if (i < na4)                  { in = a; out = oa; idx = i; }
    else if (i < na4 + nb4)       { in = b; out = ob; idx = i - na4; }
    else if (i < na4 + nb4 + nc4) { in = c; out = oc; idx = i - na4 - nb4; }
    else return;
    float4v v = ((const float4v*)in)[idx];
    half4v h;
    h[0] = (_Float16)v[0]; h[1] = (_Float16)v[1];
    h[2] = (_Float16)v[2]; h[3] = (_Float16)v[3];
    ((half4v*)out)[idx] = h;
}

// ---------------- qkv GEMM: phased schedule (m201-style port) ----------------
// C[2048][3840] = A[2048][1280] * B[3840][1280]^T + bias.
// BM=128 BN=256 BK=64, 8 waves (2x4), per-wave 64x64 (4x4 frags of 16x16x32).
// TRI-buffered LDS (144 KB, 1 block/CU): tile t+2 prefetched while computing t,
// so the tile-boundary wait is vmcnt(6) = "tile t+1 landed, t+2 still flying" —
// true counted-vmcnt with full-tile flight (T4). 4 phases per K-tile, each:
// {ds_read frags || issue 1-2 gload_lds} -> barrier -> setprio(1) -> 8 MFMA
// -> setprio(0) -> barrier  (T3 interleave + T5). XOR-swizzled LDS (T2) via
// inverse-swizzled global source: phys col16 = logical col16 ^ (row & 7).
__global__ __launch_bounds__(512) void gemm_qkv(
    const _Float16* __restrict__ A,   // [2048][1280]
    const _Float16* __restrict__ B,   // [3840][1280]
    const float*    __restrict__ bias,
    _Float16*       __restrict__ C)   // [2048][3840]
{
    constexpr int K = HID, N = 3 * HID;
    constexpr int BM = 128, BN = 256, BK = 64;
    constexpr int NT = K / BK;                 // 20 K-tiles
    constexpr int ACH = BM * BK * 2 / 1024;    // 16 A-chunks (1KB each)
    constexpr int CH = 6;                      // chunks per wave per tile

    __shared__ _Float16 As[3][BM * BK];
    __shared__ _Float16 Bs[3][BN * BK];

    const int t = threadIdx.x;
    const int lane = t & 63, wave = t >> 6;
    const int g = lane >> 4, r = lane & 15;
    const int wr = (wave >> 2) * 64, wc = (wave & 3) * 64;
    const int row_a0 = blockIdx.x * BM, row_b0 = blockIdx.y * BN;

    const int srow = lane >> 3;
    const int scol = ((lane & 7) ^ (lane >> 3)) * 8;

    // stage chunk c (wave-uniform) of K-tile tt into buffer b
    auto stage_chunk = [&](int b, int tt, int c) {
        if (c < ACH)
            gload16(&A[(size_t)(row_a0 + c * 8 + srow) * K + tt * BK + scol],
                    &As[b][c * 512]);
        else
            gload16(&B[(size_t)(row_b0 + (c - ACH) * 8 + srow) * K + tt * BK + scol],
                    &Bs[b][(c - ACH) * 512]);
    };
    auto stage_all = [&](int b, int tt) {
#pragma unroll
        for (int i = 0; i < CH; i++) stage_chunk(b, tt, wave * CH + i);
    };

    float4v acc[4][4];
    const float4v zero = {0.f, 0.f, 0.f, 0.f};
#pragma unroll
    for (int m = 0; m < 4; m++)
#pragma unroll
        for (int n = 0; n < 4; n++) acc[m][n] = zero;

    // prologue: tiles 0 and 1 in flight; wait tile 0 only
    stage_all(0, 0);
    stage_all(1, 1);
    waitcnt_vm<CH>();
    __builtin_amdgcn_s_barrier();
    cfence();

    constexpr int ph_cnt[4] = {2, 2, 1, 1};    // t+2 chunks issued per phase
    constexpr int ph_off[4] = {0, 2, 4, 5};

    int bc = 0;                                 // buffer holding tile t0
    for (int t0 = 0; t0 < NT; t0++) {
        const int bp = (bc + 2 >= 3) ? bc - 1 : bc + 2;   // buffer for t0+2
        const bool pre = (t0 + 2 < NT);
        half8v bf[4];
#pragma unroll
        for (int p = 0; p < 4; p++) {
            const int kc = p >> 1, mh = p & 1;
            // ---- ds_read frags for this phase ----
            half8v af[2];
#pragma unroll
            for (int mi = 0; mi < 2; mi++) {
                int row = wr + (mh * 2 + mi) * 16 + r;
                af[mi] = *(const half8v*)&As[bc][row * 64 + (((kc * 4 + g) ^ (r & 7)) * 8)];
            }
            if (mh == 0) {
#pragma unroll
                for (int n = 0; n < 4; n++) {
                    int row = wc + n * 16 + r;
                    bf[n] = *(const half8v*)&Bs[bc][row * 64 + (((kc * 4 + g) ^ (r & 7)) * 8)];
                }
            }
            // ---- issue this phase's share of tile t0+2 ----
            if (pre) {
#pragma unroll
                for (int j = 0; j < ph_cnt[p]; j++)
                    stage_chunk(bp, t0 + 2, wave * CH + ph_off[p] + j);
            }
            cfence();
            __builtin_amdgcn_s_barrier();
            cfence();
            // ---- MFMA cluster ----
            __builtin_amdgcn_s_setprio(1);
#pragma unroll
            for (int mi = 0; mi < 2; mi++)
#pragma unroll
                for (int n = 0; n < 4; n++)
                    acc[mh * 2 + mi][n] = __builtin_amdgcn_mfma_f32_16x16x32_f16(
                        af[mi], bf[n], acc[mh * 2 + mi][n], 0, 0, 0);
            __builtin_amdgcn_s_setprio(0);
            cfence();
            if (p == 3) {                       // tile boundary: confirm t0+1
                if (pre) waitcnt_vm<CH>();      // t0+2 keeps flying
                else     waitcnt_vm<0>();
            }
            __builtin_amdgcn_s_barrier();
            cfence();
        }
        bc = (bc + 1 >= 3) ? 0 : bc + 1;
    }

#pragma unroll
    for (int m = 0; m < 4; m++)
#pragma unroll
        for (int n = 0; n < 4; n++) {
            int col = row_b0 + wc + n * 16 + r;
            float bv = bias[col];
#pragma unroll
            for (int i = 0; i < 4; i++) {
                int row = row_a0 + wr + m * 16 + g * 4 + i;
                C[(size_t)row * N + col] = (_Float16)(acc[m][n][i] + bv);
            }
        }
}

// ---------------- proj GEMM (round-5 structure, unchanged) ----------------
template <int BM, int BN, typename OutT>
__global__ __launch_bounds__(512) void gemm_nt(
    const _Float16* __restrict__ A,
    const _Float16* __restrict__ B,
    const float*    __restrict__ bias,
    OutT*           __restrict__ C,
    int M, int N, int K)
{
    constexpr int BK = 64;
    constexpr int WM = 2, WN = 4;
    constexpr int MR = BM / WM / 16, NR = BN / WN / 16;
    constexpr int CA = BM * BK * 2 / 1024 / 8;
    constexpr int CB = BN * BK * 2 / 1024 / 8;
    constexpr int CHUNKS = CA + CB;
    __shared__ _Float16 As[2][BM * BK];
    __shared__ _Float16 Bs[2][BN * BK];

    const int t = threadIdx.x;
    const int lane = t & 63, wave = t >> 6;
    const int g = lane >> 4, r = lane & 15;
    const int wr = (wave >> 2) * (BM / WM), wc = (wave & 3) * (BN / WN);
    const int row_a0 = blockIdx.x * BM, row_b0 = blockIdx.y * BN;

    const int srow = lane >> 3;
    const int scol = ((lane & 7) ^ (lane >> 3)) * 8;

    auto stage = [&](int buf, int k0) {
#pragma unroll
        for (int i = 0; i < CA; i++) {
            int c = wave * CA + i;
            gload16(&A[(size_t)(row_a0 + c * 8 + srow) * K + k0 + scol],
                    &As[buf][c * 512]);
        }
#pragma unroll
        for (int i = 0; i < CB; i++) {
            int c = wave * CB + i;
            gload16(&B[(size_t)(row_b0 + c * 8 + srow) * K + k0 + scol],
                    &Bs[buf][c * 512]);
        }
    };

    float4v acc[MR][NR];
    const float4v zero = {0.f, 0.f, 0.f, 0.f};
#pragma unroll
    for (int m = 0; m < MR; m++)
#pragma unroll
        for (int n = 0; n < NR; n++) acc[m][n] = zero;

    stage(0, 0);

    const int nt = K / BK;
    int cur = 0;
    for (int t0 = 0; t0 < nt; t0++) {
        if (t0 + 1 < nt) {
            stage(cur ^ 1, (t0 + 1) * BK);
            waitcnt_vm<CHUNKS>();
        } else {
            waitcnt_vm<0>();
        }
        __builtin_amdgcn_s_barrier();
        cfence();

#pragma unroll
        for (int kc = 0; kc < 2; kc++) {
            half8v af[MR], bf[NR];
#pragma unroll
            for (int m = 0; m < MR; m++) {
                int row = wr + m * 16 + r;
                af[m] = *(const half8v*)&As[cur][row * 64 + (((kc * 4 + g) ^ (r & 7)) * 8)];
            }
#pragma unroll
            for (int n = 0; n < NR; n++) {
                int row = wc + n * 16 + r;
                bf[n] = *(const half8v*)&Bs[cur][row * 64 + (((kc * 4 + g) ^ (r & 7)) * 8)];
            }
#pragma unroll
            for (int m = 0; m < MR; m++)
#pragma unroll
                for (int n = 0; n < NR; n++)
                    acc[m][n] = __builtin_amdgcn_mfma_f32_16x16x32_f16(af[m], bf[n], acc[m][n], 0, 0, 0);
        }
        cfence();
        __builtin_amdgcn_s_barrier();
        cur ^= 1;
    }

#pragma unroll
    for (int m = 0; m < MR; m++)
#pragma unroll
        for (int n = 0; n < NR; n++) {
            int col = row_b0 + wc + n * 16 + r;
            float bv = bias[col];
#pragma unroll
            for (int i = 0; i < 4; i++) {
                int row = row_a0 + wr + m * 16 + g * 4 + i;
                C[(size_t)row * N + col] = (OutT)(acc[m][n][i] + bv);
            }
        }
}

// ---------------- windowed attention with fused RoPE ----------------
__global__ __launch_bounds__(256) void attn_kernel(const _Float16* __restrict__ qkv,
                                                   const float* __restrict__ cosb,
                                                   const float* __restrict__ sinb,
                                                   _Float16* __restrict__ attn)
{
    __shared__ _Float16 Qs[64][88], Ks[64][88], Vs[64][88];
    const int w = blockIdx.x, h = blockIdx.y;
    const int t = threadIdx.x, lane = t & 63, wave = t >> 6;
    const int g = lane >> 4, r = lane & 15;
    const int s0 = w * WIN;

#pragma unroll
    for (int i = 0; i < 5; i++) {
        int c = t + 256 * i;
        int row = c / 20, cc = (c % 20) * 4;
        int s = s0 + row;
        size_t base = (size_t)s * (3 * HID) + h * HD;
        int pc = (cc < 40) ? cc + 40 : cc - 40;
        float sign = (cc < 40) ? -1.f : 1.f;
        half4v q  = *(const half4v*)&qkv[base + cc];
        half4v qp = *(const half4v*)&qkv[base + pc];
        half4v k  = *(const half4v*)&qkv[base + HID + cc];
        half4v kp = *(const half4v*)&qkv[base + HID + pc];
        half4v v  = *(const half4v*)&qkv[base + 2 * HID + cc];
        float4v cs = *(const float4v*)&cosb[(size_t)s * HD + cc];
        float4v sn = *(const float4v*)&sinb[(size_t)s * HD + cc];
        half4v qo, ko;
#pragma unroll
        for (int j = 0; j < 4; j++) {
            qo[j] = (_Float16)((float)q[j] * cs[j] + sign * (float)qp[j] * sn[j]);
            ko[j] = (_Float16)((float)k[j] * cs[j] + sign * (float)kp[j] * sn[j]);
        }
        *(half4v*)&Qs[row][cc] = qo;
        *(half4v*)&Ks[row][cc] = ko;
        *(half4v*)&Vs[row][cc] = v;
    }
    __syncthreads();

    float4v sc[4];
    const float4v zero = {0.f, 0.f, 0.f, 0.f};
#pragma unroll
    for (int kt = 0; kt < 4; kt++) sc[kt] = zero;
#pragma unroll
    for (int hc = 0; hc < 5; hc++) {
        half4v qf = *(const half4v*)&Qs[wave * 16 + r][hc * 16 + g * 4];
#pragma unroll
        for (int kt = 0; kt < 4; kt++) {
            half4v kf = *(const half4v*)&Ks[kt * 16 + r][hc * 16 + g * 4];
            sc[kt] = __builtin_amdgcn_mfma_f32_16x16x16f16(kf, qf, sc[kt], 0, 0, 0);
        }
    }

    const float scale = 0.11180339887498948f;
    float mx = -1e30f;
#pragma unroll
    for (int kt = 0; kt < 4; kt++)
#pragma unroll
        for (int i = 0; i < 4; i++) { sc[kt][i] *= scale; mx = fmaxf(mx, sc[kt][i]); }
    mx = fmaxf(mx, __shfl_xor(mx, 16));
    mx = fmaxf(mx, __shfl_xor(mx, 32));
    float sum = 0.f;
#pragma unroll
    for (int kt = 0; kt < 4; kt++)
#pragma unroll
        for (int i = 0; i < 4; i++) { float e = __expf(sc[kt][i] - mx); sc[kt][i] = e; sum += e; }
    sum += __shfl_xor(sum, 16);
    sum += __shfl_xor(sum, 32);
    float inv = 1.f / sum;

    half4v pa[4];
#pragma unroll
    for (int kc = 0; kc < 4; kc++) {
        pa[kc][0] = (_Float16)(sc[kc][0] * inv);
        pa[kc][1] = (_Float16)(sc[kc][1] * inv);
        pa[kc][2] = (_Float16)(sc[kc][2] * inv);
        pa[kc][3] = (_Float16)(sc[kc][3] * inv);
    }

#pragma unroll
    for (int n = 0; n < 5; n++) {
        float4v o = zero;
#pragma unroll
        for (int kc = 0; kc < 4; kc++) {
            half4v vf;
#pragma unroll
            for (int j = 0; j < 4; j++) vf[j] = Vs[kc * 16 + g * 4 + j][n * 16 + r];
            o = __builtin_amdgcn_mfma_f32_16x16x16f16(pa[kc], vf, o, 0, 0, 0);
        }
#pragma unroll
        for (int i = 0; i < 4; i++) {
            int qrow = s0 + wave * 16 + g * 4 + i;
            attn[(size_t)qrow * HID + h * HD + n * 16 + r] = (_Float16)o[i];
        }
    }
}

// ---------------- launch ----------------
extern "C" void kernel_launch(void* const* d_in, const int* in_sizes, int n_in,
                              void* d_out, int out_size, void* d_ws, size_t ws_size,
                              hipStream_t stream)
{
    const float* hidden = (const float*)d_in[0];
    const float* cosb   = (const float*)d_in[1];
    const float* sinb   = (const float*)d_in[2];
    const float* qkv_w  = (const float*)d_in[3];
    const float* qkv_b  = (const float*)d_in[4];
    const float* proj_w = (const float*)d_in[5];
    const float* proj_b = (const float*)d_in[6];

    _Float16* hidden16 = (_Float16*)d_ws;
    _Float16* qkvw16   = hidden16 + (size_t)S_LEN * HID;
    _Float16* projw16  = qkvw16 + (size_t)3 * HID * HID;
    _Float16* qkv16    = projw16 + (size_t)HID * HID;
    _Float16* attn16   = qkv16 + (size_t)S_LEN * 3 * HID;

    const int na4 = S_LEN * HID / 4, nb4 = 3 * HID * HID / 4, nc4 = HID * HID / 4;
    cvt_all<<<(na4 + nb4 + nc4 + 255) / 256, 256, 0, stream>>>(
        hidden, hidden16, na4, qkv_w, qkvw16, nb4, proj_w, projw16, nc4);

    // qkv: 128x256 tiles -> (16,15) = 240 blocks, 8 waves, phased schedule
    gemm_qkv<<<dim3(S_LEN / 128, 3 * HID / 256), 512, 0, stream>>>(
        hidden16, qkvw16, qkv_b, qkv16);

    attn_kernel<<<dim3(NWIN, NH), 256, 0, stream>>>(qkv16, cosb, sinb, attn16);

    // proj: 64x128 tiles -> 320 blocks (round-5 structure)
    gemm_nt<64, 128, float><<<dim3(S_LEN / 64, HID / 128), 512, 0, stream>>>(
        attn16, projw16, proj_b, (float*)d_out, S_LEN, HID, HID);
}

// Round 7
// 66.759 us; speedup vs baseline: 1.0197x; 1.0197x over previous
//
#include <hip/hip_runtime.h>

#define S_LEN 2048
#define HID   1280
#define NH    16
#define HD    80
#define WIN   64
#define NWIN  (S_LEN / WIN)

typedef _Float16 half4v __attribute__((ext_vector_type(4)));
typedef _Float16 half8v __attribute__((ext_vector_type(8)));
typedef float    float4v __attribute__((ext_vector_type(4)));

// async global->LDS, 16B per lane. LDS dest = wave-uniform base (HW adds lane*16);
// global src is per-lane.
__device__ __forceinline__ void gload16(const _Float16* g, _Float16* l)
{
    __builtin_amdgcn_global_load_lds((const __attribute__((address_space(1))) void*)g,
                                     (__attribute__((address_space(3))) void*)l,
                                     16, 0, 0);
}

template <int N>
__device__ __forceinline__ void waitcnt_vm()
{
    if constexpr (N == 0)      asm volatile("s_waitcnt vmcnt(0)" ::: "memory");
    else if constexpr (N == 3) asm volatile("s_waitcnt vmcnt(3)" ::: "memory");
    else if constexpr (N == 4) asm volatile("s_waitcnt vmcnt(4)" ::: "memory");
    else static_assert(N < 0, "add literal");
}

__device__ __forceinline__ void cfence() { asm volatile("" ::: "memory"); }

// ---------------- fp32 -> fp16 conversion (qkv_w only now) ----------------
__global__ void cvt_one(const float* __restrict__ in, _Float16* __restrict__ out, int n4)
{
    int i = blockIdx.x * blockDim.x + threadIdx.x;
    if (i < n4) {
        float4v v = ((const float4v*)in)[i];
        half4v h;
        h[0] = (_Float16)v[0]; h[1] = (_Float16)v[1];
        h[2] = (_Float16)v[2]; h[3] = (_Float16)v[3];
        ((half4v*)out)[i] = h;
    }
}

// ---------------- qkv GEMM: C[2048][3840] = hidden_f32 * qkvw16^T + bias ----------------
// Round-5 structure (128x128, BK=64, 8 waves 2x4, dbuf, counted prefetch) with
// A-staging fused fp32->fp16: reg-stage (global float8 -> cvt -> swizzled
// ds_write_b128); B stays gload_lds with inverse-swizzled source (rule #21).
// Swizzle: phys col16 = logical col16 ^ (row & 7) -> conflict-free ds_read_b128.
__global__ __launch_bounds__(512) void gemm_qkv(
    const float*    __restrict__ Af,   // [2048][1280] fp32
    const _Float16* __restrict__ Bh,   // [3840][1280] fp16
    const float*    __restrict__ bias,
    _Float16*       __restrict__ C)    // [2048][3840]
{
    constexpr int K = HID, N = 3 * HID;
    constexpr int BM = 128, BN = 128, BK = 64;
    constexpr int MR = 4, NR = 2;      // per-wave 64x32 of 16x16 frags (2x4 wave grid)
    constexpr int CA = 2, CB = 2;      // 1KB chunks per wave (A reg-staged, B gload_lds)
    __shared__ _Float16 As[2][BM * BK];
    __shared__ _Float16 Bs[2][BN * BK];

    const int t = threadIdx.x;
    const int lane = t & 63, wave = t >> 6;
    const int g = lane >> 4, r = lane & 15;
    const int wr = (wave >> 2) * 64, wc = (wave & 3) * 32;
    const int row_a0 = blockIdx.x * BM, row_b0 = blockIdx.y * BN;

    const int srow = lane >> 3;                       // 0..7 within chunk
    const int lcol = (lane & 7) * 8;                  // linear col (elements)
    const int scolB = ((lane & 7) ^ srow) * 8;        // inverse-swizzled B source col
    const int wcol  = ((lane & 7) ^ srow) * 8;        // swizzled A ds_write col

    float4v acc[MR][NR];
    const float4v zero = {0.f, 0.f, 0.f, 0.f};
#pragma unroll
    for (int m = 0; m < MR; m++)
#pragma unroll
        for (int n = 0; n < NR; n++) acc[m][n] = zero;

    // ---- staging helpers ----
    float4v a0[CA], a1[CA];
    auto issue = [&](int buf, int k0) {
#pragma unroll
        for (int i = 0; i < CA; i++) {                // A: fp32 -> regs
            int c = wave * CA + i;
            const float* src = &Af[(size_t)(row_a0 + c * 8 + srow) * K + k0 + lcol];
            a0[i] = *(const float4v*)src;
            a1[i] = *(const float4v*)(src + 4);
        }
#pragma unroll
        for (int i = 0; i < CB; i++) {                // B: gload_lds, pre-swizzled src
            int c = wave * CB + i;
            gload16(&Bh[(size_t)(row_b0 + c * 8 + srow) * K + k0 + scolB],
                    &Bs[buf][c * 512]);
        }
    };
    auto commitA = [&](int buf) {                     // cvt + swizzled ds_write
#pragma unroll
        for (int i = 0; i < CA; i++) {
            int c = wave * CA + i;
            half8v h;
#pragma unroll
            for (int j = 0; j < 4; j++) { h[j] = (_Float16)a0[i][j]; h[4 + j] = (_Float16)a1[i][j]; }
            *(half8v*)&As[buf][(c * 8 + srow) * 64 + wcol] = h;
        }
    };

    // prologue: tile 0
    issue(0, 0);
    commitA(0);
    __syncthreads();

    const int nt = K / BK;
    int cur = 0;
    for (int t0 = 0; t0 < nt; t0++) {
        const bool pre = (t0 + 1 < nt);
        if (pre) { issue(cur ^ 1, (t0 + 1) * BK); cfence(); }  // pin issue before compute

#pragma unroll
        for (int kc = 0; kc < 2; kc++) {
            half8v af[MR], bf[NR];
#pragma unroll
            for (int m = 0; m < MR; m++) {
                int row = wr + m * 16 + r;
                af[m] = *(const half8v*)&As[cur][row * 64 + (((kc * 4 + g) ^ (r & 7)) * 8)];
            }
#pragma unroll
            for (int n = 0; n < NR; n++) {
                int row = wc + n * 16 + r;
                bf[n] = *(const half8v*)&Bs[cur][row * 64 + (((kc * 4 + g) ^ (r & 7)) * 8)];
            }
#pragma unroll
            for (int m = 0; m < MR; m++)
#pragma unroll
                for (int n = 0; n < NR; n++)
                    acc[m][n] = __builtin_amdgcn_mfma_f32_16x16x32_f16(af[m], bf[n], acc[m][n], 0, 0, 0);
        }
        if (pre) commitA(cur ^ 1);    // A-loads had full compute phase in flight
        __syncthreads();              // drains vm+lgkm; B-gloads also had full flight
        cur ^= 1;
    }

#pragma unroll
    for (int m = 0; m < MR; m++)
#pragma unroll
        for (int n = 0; n < NR; n++) {
            int col = row_b0 + wc + n * 16 + r;
            float bv = bias[col];
#pragma unroll
            for (int i = 0; i < 4; i++) {
                int row = row_a0 + wr + m * 16 + g * 4 + i;
                C[(size_t)row * N + col] = (_Float16)(acc[m][n][i] + bv);
            }
        }
}

// ---------------- proj GEMM (round-5 structure, all-fp16 inputs) ----------------
template <int BM, int BN, typename OutT>
__global__ __launch_bounds__(512) void gemm_nt(
    const _Float16* __restrict__ A,
    const _Float16* __restrict__ B,
    const float*    __restrict__ bias,
    OutT*           __restrict__ C,
    int M, int N, int K)
{
    constexpr int BK = 64;
    constexpr int WM = 2, WN = 4;
    constexpr int MR = BM / WM / 16, NR = BN / WN / 16;
    constexpr int CA = BM * BK * 2 / 1024 / 8;
    constexpr int CB = BN * BK * 2 / 1024 / 8;
    constexpr int CHUNKS = CA + CB;
    __shared__ _Float16 As[2][BM * BK];
    __shared__ _Float16 Bs[2][BN * BK];

    const int t = threadIdx.x;
    const int lane = t & 63, wave = t >> 6;
    const int g = lane >> 4, r = lane & 15;
    const int wr = (wave >> 2) * (BM / WM), wc = (wave & 3) * (BN / WN);
    const int row_a0 = blockIdx.x * BM, row_b0 = blockIdx.y * BN;

    const int srow = lane >> 3;
    const int scol = ((lane & 7) ^ (lane >> 3)) * 8;

    auto stage = [&](int buf, int k0) {
#pragma unroll
        for (int i = 0; i < CA; i++) {
            int c = wave * CA + i;
            gload16(&A[(size_t)(row_a0 + c * 8 + srow) * K + k0 + scol],
                    &As[buf][c * 512]);
        }
#pragma unroll
        for (int i = 0; i < CB; i++) {
            int c = wave * CB + i;
            gload16(&B[(size_t)(row_b0 + c * 8 + srow) * K + k0 + scol],
                    &Bs[buf][c * 512]);
        }
    };

    float4v acc[MR][NR];
    const float4v zero = {0.f, 0.f, 0.f, 0.f};
#pragma unroll
    for (int m = 0; m < MR; m++)
#pragma unroll
        for (int n = 0; n < NR; n++) acc[m][n] = zero;

    stage(0, 0);

    const int nt = K / BK;
    int cur = 0;
    for (int t0 = 0; t0 < nt; t0++) {
        if (t0 + 1 < nt) {
            stage(cur ^ 1, (t0 + 1) * BK);
            waitcnt_vm<CHUNKS>();
        } else {
            waitcnt_vm<0>();
        }
        __builtin_amdgcn_s_barrier();
        cfence();

#pragma unroll
        for (int kc = 0; kc < 2; kc++) {
            half8v af[MR], bf[NR];
#pragma unroll
            for (int m = 0; m < MR; m++) {
                int row = wr + m * 16 + r;
                af[m] = *(const half8v*)&As[cur][row * 64 + (((kc * 4 + g) ^ (r & 7)) * 8)];
            }
#pragma unroll
            for (int n = 0; n < NR; n++) {
                int row = wc + n * 16 + r;
                bf[n] = *(const half8v*)&Bs[cur][row * 64 + (((kc * 4 + g) ^ (r & 7)) * 8)];
            }
#pragma unroll
            for (int m = 0; m < MR; m++)
#pragma unroll
                for (int n = 0; n < NR; n++)
                    acc[m][n] = __builtin_amdgcn_mfma_f32_16x16x32_f16(af[m], bf[n], acc[m][n], 0, 0, 0);
        }
        cfence();
        __builtin_amdgcn_s_barrier();
        cur ^= 1;
    }

#pragma unroll
    for (int m = 0; m < MR; m++)
#pragma unroll
        for (int n = 0; n < NR; n++) {
            int col = row_b0 + wc + n * 16 + r;
            float bv = bias[col];
#pragma unroll
            for (int i = 0; i < 4; i++) {
                int row = row_a0 + wr + m * 16 + g * 4 + i;
                C[(size_t)row * N + col] = (OutT)(acc[m][n][i] + bv);
            }
        }
}

// ---------------- windowed attention with fused RoPE + proj_w conversion ----------------
__global__ __launch_bounds__(256) void attn_kernel(const _Float16* __restrict__ qkv,
                                                   const float* __restrict__ cosb,
                                                   const float* __restrict__ sinb,
                                                   _Float16* __restrict__ attn,
                                                   const float* __restrict__ projw,
                                                   _Float16* __restrict__ projw16)
{
    __shared__ _Float16 Qs[64][88], Ks[64][88], Vs[64][88];
    const int w = blockIdx.x, h = blockIdx.y;
    const int t = threadIdx.x, lane = t & 63, wave = t >> 6;
    const int g = lane >> 4, r = lane & 15;
    const int s0 = w * WIN;

#pragma unroll
    for (int i = 0; i < 5; i++) {
        int c = t + 256 * i;
        int row = c / 20, cc = (c % 20) * 4;
        int s = s0 + row;
        size_t base = (size_t)s * (3 * HID) + h * HD;
        int pc = (cc < 40) ? cc + 40 : cc - 40;
        float sign = (cc < 40) ? -1.f : 1.f;
        half4v q  = *(const half4v*)&qkv[base + cc];
        half4v qp = *(const half4v*)&qkv[base + pc];
        half4v k  = *(const half4v*)&qkv[base + HID + cc];
        half4v kp = *(const half4v*)&qkv[base + HID + pc];
        half4v v  = *(const half4v*)&qkv[base + 2 * HID + cc];
        float4v cs = *(const float4v*)&cosb[(size_t)s * HD + cc];
        float4v sn = *(const float4v*)&sinb[(size_t)s * HD + cc];
        half4v qo, ko;
#pragma unroll
        for (int j = 0; j < 4; j++) {
            qo[j] = (_Float16)((float)q[j] * cs[j] + sign * (float)qp[j] * sn[j]);
            ko[j] = (_Float16)((float)k[j] * cs[j] + sign * (float)kp[j] * sn[j]);
        }
        *(half4v*)&Qs[row][cc] = qo;
        *(half4v*)&Ks[row][cc] = ko;
        *(half4v*)&Vs[row][cc] = v;
    }
    __syncthreads();

    float4v sc[4];
    const float4v zero = {0.f, 0.f, 0.f, 0.f};
#pragma unroll
    for (int kt = 0; kt < 4; kt++) sc[kt] = zero;
#pragma unroll
    for (int hc = 0; hc < 5; hc++) {
        half4v qf = *(const half4v*)&Qs[wave * 16 + r][hc * 16 + g * 4];
#pragma unroll
        for (int kt = 0; kt < 4; kt++) {
            half4v kf = *(const half4v*)&Ks[kt * 16 + r][hc * 16 + g * 4];
            sc[kt] = __builtin_amdgcn_mfma_f32_16x16x16f16(kf, qf, sc[kt], 0, 0, 0);
        }
    }

    const float scale = 0.11180339887498948f;
    float mx = -1e30f;
#pragma unroll
    for (int kt = 0; kt < 4; kt++)
#pragma unroll
        for (int i = 0; i < 4; i++) { sc[kt][i] *= scale; mx = fmaxf(mx, sc[kt][i]); }
    mx = fmaxf(mx, __shfl_xor(mx, 16));
    mx = fmaxf(mx, __shfl_xor(mx, 32));
    float sum = 0.f;
#pragma unroll
    for (int kt = 0; kt < 4; kt++)
#pragma unroll
        for (int i = 0; i < 4; i++) { float e = __expf(sc[kt][i] - mx); sc[kt][i] = e; sum += e; }
    sum += __shfl_xor(sum, 16);
    sum += __shfl_xor(sum, 32);
    float inv = 1.f / sum;

    half4v pa[4];
#pragma unroll
    for (int kc = 0; kc < 4; kc++) {
        pa[kc][0] = (_Float16)(sc[kc][0] * inv);
        pa[kc][1] = (_Float16)(sc[kc][1] * inv);
        pa[kc][2] = (_Float16)(sc[kc][2] * inv);
        pa[kc][3] = (_Float16)(sc[kc][3] * inv);
    }

#pragma unroll
    for (int n = 0; n < 5; n++) {
        float4v o = zero;
#pragma unroll
        for (int kc = 0; kc < 4; kc++) {
            half4v vf;
#pragma unroll
            for (int j = 0; j < 4; j++) vf[j] = Vs[kc * 16 + g * 4 + j][n * 16 + r];
            o = __builtin_amdgcn_mfma_f32_16x16x16f16(pa[kc], vf, o, 0, 0, 0);
        }
#pragma unroll
        for (int i = 0; i < 4; i++) {
            int qrow = s0 + wave * 16 + g * 4 + i;
            attn[(size_t)qrow * HID + h * HD + n * 16 + r] = (_Float16)o[i];
        }
    }

    // ---- fused proj_w fp32->fp16 conversion (hides under attn latency;
    //      completes before proj launches via stream order) ----
    const int np4 = HID * HID / 4;
    const int bid = blockIdx.y * gridDim.x + blockIdx.x;
    const int stride = gridDim.x * gridDim.y * 256;
    for (int i = bid * 256 + t; i < np4; i += stride) {
        float4v v = ((const float4v*)projw)[i];
        half4v hh;
        hh[0] = (_Float16)v[0]; hh[1] = (_Float16)v[1];
        hh[2] = (_Float16)v[2]; hh[3] = (_Float16)v[3];
        ((half4v*)projw16)[i] = hh;
    }
}

// ---------------- launch ----------------
extern "C" void kernel_launch(void* const* d_in, const int* in_sizes, int n_in,
                              void* d_out, int out_size, void* d_ws, size_t ws_size,
                              hipStream_t stream)
{
    const float* hidden = (const float*)d_in[0];
    const float* cosb   = (const float*)d_in[1];
    const float* sinb   = (const float*)d_in[2];
    const float* qkv_w  = (const float*)d_in[3];
    const float* qkv_b  = (const float*)d_in[4];
    const float* proj_w = (const float*)d_in[5];
    const float* proj_b = (const float*)d_in[6];

    _Float16* qkvw16  = (_Float16*)d_ws;                       // 3840*1280
    _Float16* projw16 = qkvw16 + (size_t)3 * HID * HID;        // 1280*1280
    _Float16* qkv16   = projw16 + (size_t)HID * HID;           // 2048*3840
    _Float16* attn16  = qkv16 + (size_t)S_LEN * 3 * HID;       // 2048*1280

    const int nb4 = 3 * HID * HID / 4;
    cvt_one<<<(nb4 + 255) / 256, 256, 0, stream>>>(qkv_w, qkvw16, nb4);

    // qkv: fp32-A fused staging, 128x128 tiles, 512 thr -> 480 blocks
    gemm_qkv<<<dim3(S_LEN / 128, 3 * HID / 128), 512, 0, stream>>>(
        hidden, qkvw16, qkv_b, qkv16);

    attn_kernel<<<dim3(NWIN, NH), 256, 0, stream>>>(
        qkv16, cosb, sinb, attn16, proj_w, projw16);

    // proj: 64x128 tiles -> 320 blocks
    gemm_nt<64, 128, float><<<dim3(S_LEN / 64, HID / 128), 512, 0, stream>>>(
        attn16, projw16, proj_b, (float*)d_out, S_LEN, HID, HID);
}